// Round 12
// baseline (429.879 us; speedup 1.0000x reference)
//
#include <hip/hip_runtime.h>
#include <math.h>

#define N_NODES 100000
#define N_EDGES 1600000
#define D 128
#define L_LAYERS 3
#define P_STATS 7
#define B_GRAPHS 64
#define BN_EPS 1e-5f
#define NEG_SLOPE 0.2f

#define NB 196        // buckets of 512 dst nodes
#define BCAP 10240
#define EPB 6400

typedef __attribute__((ext_vector_type(8))) short bf16x8;
typedef __attribute__((ext_vector_type(4))) float f32x4;

static __device__ __forceinline__ short f2bf(float f) {
    union { float f; unsigned u; } v;
    v.f = f;
    unsigned r = v.u + 0x7fffu + ((v.u >> 16) & 1u);  // RNE
    return (short)(r >> 16);
}

static __device__ __forceinline__ float bf2f(short s) {
    union { unsigned u; float f; } v;
    v.u = ((unsigned)(unsigned short)s) << 16;
    return v.f;
}

// ---------------- CSR build (bucketed) ----------------

__global__ void zero_n_kernel(int* __restrict__ p, int n) {
    int i = blockIdx.x * blockDim.x + threadIdx.x;
    if (i < n) p[i] = 0;
}

// Pass A: partition edges into NB append-buffers. No LDS edge staging
// (dst re-read from L2 in pass 2) -> 2.4KB LDS, high occupancy.
__global__ __launch_bounds__(256) void bucketA_kernel(const int* __restrict__ src,
                                                      const int* __restrict__ dst,
                                                      int* __restrict__ bucket_cnt,
                                                      int2* __restrict__ bucketbuf) {
    __shared__ int hist[NB], base[NB], loc[NB];
    const int tid = threadIdx.x;
    const int e0 = blockIdx.x * EPB;
    for (int i = tid; i < NB; i += 256) { hist[i] = 0; loc[i] = 0; }
    __syncthreads();
    for (int i = tid; i < EPB; i += 256) {
        int d = dst[e0 + i];
        atomicAdd(&hist[d >> 9], 1);
    }
    __syncthreads();
    for (int i = tid; i < NB; i += 256)
        base[i] = hist[i] ? atomicAdd(&bucket_cnt[i], hist[i]) : 0;
    __syncthreads();
    for (int i = tid; i < EPB; i += 256) {
        int s = src[e0 + i];
        int d = dst[e0 + i];
        int b = d >> 9;
        int off = atomicAdd(&loc[b], 1);
        int idx = base[b] + off;
        if (idx < BCAP) bucketbuf[(size_t)b * BCAP + idx] = make_int2(s, d);
    }
}

__global__ __launch_bounds__(256) void bucketB1_kernel(const int* __restrict__ bucket_cnt,
                                                       const int2* __restrict__ bucketbuf,
                                                       int* __restrict__ deg) {
    __shared__ int hist[512];
    const int b = blockIdx.x;
    for (int i = threadIdx.x; i < 512; i += 256) hist[i] = 0;
    __syncthreads();
    int cnt = min(bucket_cnt[b], BCAP);
    for (int i = threadIdx.x; i < cnt; i += 256) {
        int d = bucketbuf[(size_t)b * BCAP + i].y;
        atomicAdd(&hist[d & 511], 1);
    }
    __syncthreads();
    int nbase = b << 9;
    for (int i = threadIdx.x; i < 512; i += 256) {
        int node = nbase + i;
        if (node < N_NODES) deg[node] = hist[i];
    }
}

__global__ __launch_bounds__(256) void bucketB2_kernel(const int* __restrict__ bucket_cnt,
                                                       const int2* __restrict__ bucketbuf,
                                                       int* __restrict__ cursor,
                                                       int* __restrict__ csr_src) {
    const int b = blockIdx.x;
    int cnt = min(bucket_cnt[b], BCAP);
    for (int i = threadIdx.x; i < cnt; i += 256) {
        int2 p = bucketbuf[(size_t)b * BCAP + i];
        int pos = atomicAdd(&cursor[p.y], 1);
        csr_src[pos] = p.x;
    }
}

// ---------------- scans ----------------

__global__ void scan1_kernel(const int* __restrict__ deg, int* __restrict__ incl,
                             int* __restrict__ bsum) {
    __shared__ int s[256];
    const int tid = threadIdx.x;
    const int base = blockIdx.x * 2048;
    int v[8];
    int sum = 0;
    const int idx0 = base + tid * 8;
#pragma unroll
    for (int i = 0; i < 8; ++i) {
        int idx = idx0 + i;
        int d = (idx < N_NODES) ? deg[idx] : 0;
        sum += d;
        v[i] = sum;
    }
    s[tid] = sum;
    __syncthreads();
    for (int off = 1; off < 256; off <<= 1) {
        int t = (tid >= off) ? s[tid - off] : 0;
        __syncthreads();
        s[tid] += t;
        __syncthreads();
    }
    int prev = (tid > 0) ? s[tid - 1] : 0;
#pragma unroll
    for (int i = 0; i < 8; ++i) {
        int idx = idx0 + i;
        if (idx < N_NODES) incl[idx] = v[i] + prev;
    }
    if (tid == 255) bsum[blockIdx.x] = s[255];
}

__global__ void scan2_kernel(int* __restrict__ bsum, int nb) {
    if (threadIdx.x == 0 && blockIdx.x == 0) {
        int run = 0;
        for (int i = 0; i < nb; ++i) { int t = bsum[i]; bsum[i] = run; run += t; }
    }
}

__global__ void scan3_kernel(const int* __restrict__ deg, const int* __restrict__ incl,
                             const int* __restrict__ bsum, int* __restrict__ start,
                             int* __restrict__ cursor) {
    int i = blockIdx.x * blockDim.x + threadIdx.x;
    if (i < N_NODES) {
        int inc = incl[i] + bsum[i >> 11];
        int st = inc - deg[i];
        start[i] = st;
        cursor[i] = st;
    }
    if (i == 0) start[N_NODES] = N_EDGES;
}

// ---------------- per-graph stat projections ----------------
__global__ void gproj_kernel(const float* __restrict__ gs, const float* __restrict__ statWs,
                             const float* __restrict__ statBs, float* __restrict__ gproj) {
    int b = blockIdx.x;
    int l = blockIdx.y;
    int j = threadIdx.x;
    float acc = statBs[l * D + j];
#pragma unroll
    for (int p = 0; p < P_STATS; ++p) {
        float g = gs[b * P_STATS + p];
        if (g != g) g = -100.0f;
        acc += g * statWs[(l * P_STATS + p) * D + j];
    }
    gproj[(l * B_GRAPHS + b) * D + j] = acc;
}

// ---------------- weight convert: W[k][n] f32 -> Wt[n][k] bf16 ----------------
__global__ void wconv_kernel(const float* __restrict__ W1s, const float* __restrict__ W2s,
                             const float* __restrict__ fcW, short* __restrict__ wt) {
    int mid = blockIdx.y;
    const float* src = (mid < 3) ? (W1s + mid * D * D)
                                 : ((mid < 6) ? (W2s + (mid - 3) * D * D) : fcW);
    short* dstm = wt + mid * D * D;
    int i = blockIdx.x * 256 + threadIdx.x;
    int k = i >> 7, n = i & 127;
    dstm[n * D + k] = f2bf(src[i]);
}

// ---------------- aggregation over g + fused bias/LReLU/BN epilogue ----------------
// z = BN(LReLU(g[own] + sum g[src] + b1)). 16 lanes/node, unroll-4 (proven config).
__global__ __launch_bounds__(256) void agg_ep_kernel(const short* __restrict__ g,
                                                     const int* __restrict__ start,
                                                     const int* __restrict__ csr_src,
                                                     const float* __restrict__ b1,
                                                     const float* __restrict__ gamma,
                                                     const float* __restrict__ beta,
                                                     const float* __restrict__ mean,
                                                     const float* __restrict__ var,
                                                     short* __restrict__ z) {
    int node = blockIdx.x * 16 + (threadIdx.x >> 4);
    int c8 = threadIdx.x & 15;
    const bf16x8* g8 = (const bf16x8*)g;

    bf16x8 own = g8[node * 16 + c8];
    float acc[8];
#pragma unroll
    for (int i = 0; i < 8; ++i) acc[i] = bf2f(own[i]);

    int s = start[node];
    int e = start[node + 1];
    int k = s;
    for (; k + 4 <= e; k += 4) {
        int sn0 = csr_src[k];
        int sn1 = csr_src[k + 1];
        int sn2 = csr_src[k + 2];
        int sn3 = csr_src[k + 3];
        bf16x8 v0 = g8[sn0 * 16 + c8];
        bf16x8 v1 = g8[sn1 * 16 + c8];
        bf16x8 v2 = g8[sn2 * 16 + c8];
        bf16x8 v3 = g8[sn3 * 16 + c8];
#pragma unroll
        for (int i = 0; i < 8; ++i) acc[i] += bf2f(v0[i]);
#pragma unroll
        for (int i = 0; i < 8; ++i) acc[i] += bf2f(v1[i]);
#pragma unroll
        for (int i = 0; i < 8; ++i) acc[i] += bf2f(v2[i]);
#pragma unroll
        for (int i = 0; i < 8; ++i) acc[i] += bf2f(v3[i]);
    }
    for (; k < e; ++k) {
        int sn0 = csr_src[k];
        bf16x8 v0 = g8[sn0 * 16 + c8];
#pragma unroll
        for (int i = 0; i < 8; ++i) acc[i] += bf2f(v0[i]);
    }

    // epilogue: + b1 -> LeakyReLU -> BN
    const int f0 = c8 * 8;
    float4 bb0 = *(const float4*)&b1[f0];
    float4 bb1 = *(const float4*)&b1[f0 + 4];
    float4 gm0 = *(const float4*)&gamma[f0];
    float4 gm1 = *(const float4*)&gamma[f0 + 4];
    float4 bt0 = *(const float4*)&beta[f0];
    float4 bt1 = *(const float4*)&beta[f0 + 4];
    float4 mn0 = *(const float4*)&mean[f0];
    float4 mn1 = *(const float4*)&mean[f0 + 4];
    float4 vr0 = *(const float4*)&var[f0];
    float4 vr1 = *(const float4*)&var[f0 + 4];
    float bbv[8] = {bb0.x, bb0.y, bb0.z, bb0.w, bb1.x, bb1.y, bb1.z, bb1.w};
    float gmv[8] = {gm0.x, gm0.y, gm0.z, gm0.w, gm1.x, gm1.y, gm1.z, gm1.w};
    float btv[8] = {bt0.x, bt0.y, bt0.z, bt0.w, bt1.x, bt1.y, bt1.z, bt1.w};
    float mnv[8] = {mn0.x, mn0.y, mn0.z, mn0.w, mn1.x, mn1.y, mn1.z, mn1.w};
    float vrv[8] = {vr0.x, vr0.y, vr0.z, vr0.w, vr1.x, vr1.y, vr1.z, vr1.w};

    short pk[8];
#pragma unroll
    for (int i = 0; i < 8; ++i) {
        float t = acc[i] + bbv[i];
        t = (t > 0.f) ? t : NEG_SLOPE * t;
        float sc = gmv[i] * rsqrtf(vrv[i] + BN_EPS);
        t = t * sc + (btv[i] - mnv[i] * sc);
        pk[i] = f2bf(t);
    }
    *(bf16x8*)&z[node * D + f0] = *(bf16x8*)pk;
}

// ---------------- init GEMM: g0 = bf16(x) @ W1_0 ----------------
// 64-node tile, 4 waves; coalesced staged output.
__global__ __launch_bounds__(256, 4) void initgemm_kernel(const float* __restrict__ x,
                                                          const short* __restrict__ Wt,
                                                          short* __restrict__ g_out) {
    __shared__ short sy[64 * 128];
    const int tid = threadIdx.x;
    const int wid = tid >> 6;
    const int lane = tid & 63;
    const int lr = lane & 15;
    const int lk = lane >> 4;

    const int nlBase = (wid >> 1) * 32;
    const int nodeBase = blockIdx.x * 64 + nlBase;
    const int featBase = (wid & 1) * 64;

    int nIdx[2];
#pragma unroll
    for (int mt = 0; mt < 2; ++mt) {
        int n = nodeBase + mt * 16 + lr;
        nIdx[mt] = (n < N_NODES) ? n : (N_NODES - 1);
    }

    f32x4 acc[4][2];
#pragma unroll
    for (int ft = 0; ft < 4; ++ft)
#pragma unroll
        for (int mt = 0; mt < 2; ++mt)
            acc[ft][mt] = (f32x4)(0.0f);

#pragma unroll
    for (int kt = 0; kt < 4; ++kt) {
        bf16x8 wfk[4];
#pragma unroll
        for (int ft = 0; ft < 4; ++ft)
            wfk[ft] = *(const bf16x8*)&Wt[(featBase + ft * 16 + lr) * D + kt * 32 + lk * 8];
        bf16x8 mf[2];
#pragma unroll
        for (int mt = 0; mt < 2; ++mt) {
            const float4* xp = (const float4*)&x[nIdx[mt] * D + kt * 32 + lk * 8];
            float4 a = xp[0], b = xp[1];
            short q[8];
            q[0] = f2bf(a.x); q[1] = f2bf(a.y); q[2] = f2bf(a.z); q[3] = f2bf(a.w);
            q[4] = f2bf(b.x); q[5] = f2bf(b.y); q[6] = f2bf(b.z); q[7] = f2bf(b.w);
            mf[mt] = *(bf16x8*)q;
        }
#pragma unroll
        for (int ft = 0; ft < 4; ++ft)
#pragma unroll
            for (int mt = 0; mt < 2; ++mt)
                acc[ft][mt] = __builtin_amdgcn_mfma_f32_16x16x32_bf16(wfk[ft], mf[mt],
                                                                      acc[ft][mt], 0, 0, 0);
    }

    // stage to LDS (swizzled) then coalesced copy-out
#pragma unroll
    for (int ft = 0; ft < 4; ++ft) {
        int f0 = featBase + ft * 16 + lk * 4;
#pragma unroll
        for (int mt = 0; mt < 2; ++mt) {
            int nl = nlBase + mt * 16 + lr;
            short4 pk;
#pragma unroll
            for (int r = 0; r < 4; ++r) ((short*)&pk)[r] = f2bf(acc[ft][mt][r]);
            int byteoff = nl * 256 + f0 * 2;
            byteoff ^= (nl & 7) << 4;
            *(short4*)((char*)sy + byteoff) = pk;
        }
    }
    __syncthreads();
#pragma unroll
    for (int it = 0; it < 4; ++it) {
        int c = tid + it * 256;
        int nl = c >> 4;
        int c8 = c & 15;
        int node = blockIdx.x * 64 + nl;
        if (node < N_NODES) {
            int byteoff = nl * 256 + c8 * 16;
            byteoff ^= (nl & 7) << 4;
            bf16x8 v = *(const bf16x8*)((char*)sy + byteoff);
            *(bf16x8*)&g_out[node * D + c8 * 8] = v;
        }
    }
}

// ---------------- MLP: y=LReLU(z@W2+b2)+gproj -> h; g=h@Wn (or out=h@fcW+fcB) ----------------
// 64-node tile, 4 waves, 2 GEMMs (GEMM1 eliminated by linearity; agg absorbed it).
template <bool FINAL>
__global__ __launch_bounds__(256, 4) void mlp2_kernel(
    const short* __restrict__ z,
    const short* __restrict__ W2t,
    const float* __restrict__ b2,
    const float* __restrict__ gproj, const int* __restrict__ batch,
    const short* __restrict__ Wnt,   // W1_{l+1}^T or fcW^T
    const float* __restrict__ fcb,   // FINAL only
    float* __restrict__ outf, short* __restrict__ g_out) {
    __shared__ short sy[64 * 128];  // 16KB, XOR-swizzled rows
    __shared__ float sB2[128], sFC[128];

    const int tid = threadIdx.x;
    const int wid = tid >> 6;
    const int lane = tid & 63;
    const int lr = lane & 15;
    const int lk = lane >> 4;

    if (tid < 128) {
        sB2[tid] = b2[tid];
        if (FINAL) sFC[tid] = fcb[tid];
    }
    __syncthreads();

    const int nlBase = (wid >> 1) * 32;
    const int nodeBase = blockIdx.x * 64 + nlBase;
    const int featBase = (wid & 1) * 64;

    int nIdx[2];
#pragma unroll
    for (int mt = 0; mt < 2; ++mt) {
        int n = nodeBase + mt * 16 + lr;
        nIdx[mt] = (n < N_NODES) ? n : (N_NODES - 1);
    }

    f32x4 acc[4][2];
#pragma unroll
    for (int ft = 0; ft < 4; ++ft)
#pragma unroll
        for (int mt = 0; mt < 2; ++mt)
            acc[ft][mt] = (f32x4)(0.0f);

    // ---- GEMM A: z @ W2 ----
#pragma unroll
    for (int kt = 0; kt < 4; ++kt) {
        bf16x8 wfk[4];
#pragma unroll
        for (int ft = 0; ft < 4; ++ft)
            wfk[ft] = *(const bf16x8*)&W2t[(featBase + ft * 16 + lr) * D + kt * 32 + lk * 8];
        bf16x8 zf[2];
#pragma unroll
        for (int mt = 0; mt < 2; ++mt)
            zf[mt] = *(const bf16x8*)&z[nIdx[mt] * D + kt * 32 + lk * 8];
#pragma unroll
        for (int ft = 0; ft < 4; ++ft)
#pragma unroll
            for (int mt = 0; mt < 2; ++mt)
                acc[ft][mt] = __builtin_amdgcn_mfma_f32_16x16x32_bf16(wfk[ft], zf[mt],
                                                                      acc[ft][mt], 0, 0, 0);
    }

    // ---- epilogue: +b2, LReLU, +gproj -> h bf16 -> LDS (swizzled) ----
#pragma unroll
    for (int ft = 0; ft < 4; ++ft) {
        int f0 = featBase + ft * 16 + lk * 4;
#pragma unroll
        for (int mt = 0; mt < 2; ++mt) {
            int nl = nlBase + mt * 16 + lr;
            int bid = batch[nIdx[mt]];
            const float4 gp = *(const float4*)&gproj[bid * D + f0];
            short4 pk;
            float v0 = acc[ft][mt][0] + sB2[f0 + 0]; v0 = (v0 > 0.f) ? v0 : NEG_SLOPE * v0; v0 += gp.x;
            float v1 = acc[ft][mt][1] + sB2[f0 + 1]; v1 = (v1 > 0.f) ? v1 : NEG_SLOPE * v1; v1 += gp.y;
            float v2 = acc[ft][mt][2] + sB2[f0 + 2]; v2 = (v2 > 0.f) ? v2 : NEG_SLOPE * v2; v2 += gp.z;
            float v3 = acc[ft][mt][3] + sB2[f0 + 3]; v3 = (v3 > 0.f) ? v3 : NEG_SLOPE * v3; v3 += gp.w;
            pk.x = f2bf(v0); pk.y = f2bf(v1); pk.z = f2bf(v2); pk.w = f2bf(v3);
            int byteoff = nl * 256 + f0 * 2;
            byteoff ^= (nl & 7) << 4;
            *(short4*)((char*)sy + byteoff) = pk;
        }
    }
    __syncthreads();

    // ---- GEMM B: h @ Wn (h from LDS) ----
#pragma unroll
    for (int ft = 0; ft < 4; ++ft)
#pragma unroll
        for (int mt = 0; mt < 2; ++mt)
            acc[ft][mt] = (f32x4)(0.0f);

#pragma unroll
    for (int kt = 0; kt < 4; ++kt) {
        bf16x8 wfk[4];
#pragma unroll
        for (int ft = 0; ft < 4; ++ft)
            wfk[ft] = *(const bf16x8*)&Wnt[(featBase + ft * 16 + lr) * D + kt * 32 + lk * 8];
        bf16x8 hf[2];
#pragma unroll
        for (int mt = 0; mt < 2; ++mt) {
            int nl = nlBase + mt * 16 + lr;
            int byteoff = nl * 256 + kt * 64 + lk * 16;
            byteoff ^= (nl & 7) << 4;
            hf[mt] = *(const bf16x8*)((char*)sy + byteoff);
        }
#pragma unroll
        for (int ft = 0; ft < 4; ++ft)
#pragma unroll
            for (int mt = 0; mt < 2; ++mt)
                acc[ft][mt] = __builtin_amdgcn_mfma_f32_16x16x32_bf16(wfk[ft], hf[mt],
                                                                      acc[ft][mt], 0, 0, 0);
    }

    if (FINAL) {
        // out = h @ fcW + fcB (f32)
#pragma unroll
        for (int mt = 0; mt < 2; ++mt) {
            int node = nodeBase + mt * 16 + lr;
            if (node >= N_NODES) continue;
#pragma unroll
            for (int ft = 0; ft < 4; ++ft) {
                int f0 = featBase + ft * 16 + lk * 4;
                float4 o;
                o.x = acc[ft][mt][0] + sFC[f0 + 0];
                o.y = acc[ft][mt][1] + sFC[f0 + 1];
                o.z = acc[ft][mt][2] + sFC[f0 + 2];
                o.w = acc[ft][mt][3] + sFC[f0 + 3];
                *(float4*)&outf[node * D + f0] = o;
            }
        }
        return;
    }

    // g = h @ W1_{l+1}, no bias (bias added in agg epilogue); coalesced staged store
    __syncthreads();  // all waves done reading sy
#pragma unroll
    for (int ft = 0; ft < 4; ++ft) {
        int f0 = featBase + ft * 16 + lk * 4;
#pragma unroll
        for (int mt = 0; mt < 2; ++mt) {
            int nl = nlBase + mt * 16 + lr;
            short4 pk;
#pragma unroll
            for (int r = 0; r < 4; ++r) ((short*)&pk)[r] = f2bf(acc[ft][mt][r]);
            int byteoff = nl * 256 + f0 * 2;
            byteoff ^= (nl & 7) << 4;
            *(short4*)((char*)sy + byteoff) = pk;
        }
    }
    __syncthreads();
#pragma unroll
    for (int it = 0; it < 4; ++it) {
        int c = tid + it * 256;
        int nl = c >> 4;
        int c8 = c & 15;
        int node = blockIdx.x * 64 + nl;
        if (node < N_NODES) {
            int byteoff = nl * 256 + c8 * 16;
            byteoff ^= (nl & 7) << 4;
            bf16x8 v = *(const bf16x8*)((char*)sy + byteoff);
            *(bf16x8*)&g_out[node * D + c8 * 8] = v;
        }
    }
}

// ---------------- launch ----------------

extern "C" void kernel_launch(void* const* d_in, const int* in_sizes, int n_in,
                              void* d_out, int out_size, void* d_ws, size_t ws_size,
                              hipStream_t stream) {
    const float* x = (const float*)d_in[0];
    const int* ei = (const int*)d_in[1];
    const int* src = ei;
    const int* dst = ei + N_EDGES;
    const int* batch = (const int*)d_in[2];
    const float* gs = (const float*)d_in[3];
    const float* W1s = (const float*)d_in[4];
    const float* b1s = (const float*)d_in[5];
    const float* gammas = (const float*)d_in[6];
    const float* betas = (const float*)d_in[7];
    const float* means = (const float*)d_in[8];
    const float* vars = (const float*)d_in[9];
    const float* W2s = (const float*)d_in[10];
    const float* b2s = (const float*)d_in[11];
    const float* statWs = (const float*)d_in[12];
    const float* statBs = (const float*)d_in[13];
    const float* fcW = (const float*)d_in[14];
    const float* fcB = (const float*)d_in[15];
    float* out = (float*)d_out;

    char* ws = (char*)d_ws;
    auto alloc = [&](size_t bytes) {
        char* p = ws;
        ws += (bytes + 255) / 256 * 256;
        return p;
    };
    int* deg = (int*)alloc(N_NODES * sizeof(int));
    int* incl = (int*)alloc(N_NODES * sizeof(int));
    int* bsum = (int*)alloc(64 * sizeof(int));
    int* start = (int*)alloc((N_NODES + 1) * sizeof(int));
    int* cursor = (int*)alloc(N_NODES * sizeof(int));
    int* csr_src = (int*)alloc(N_EDGES * sizeof(int));
    int* bucket_cnt = (int*)alloc(NB * sizeof(int));
    int2* bucketbuf = (int2*)alloc((size_t)NB * BCAP * sizeof(int2));
    float* gproj = (float*)alloc((size_t)L_LAYERS * B_GRAPHS * D * sizeof(float));
    short* wt = (short*)alloc((size_t)7 * D * D * sizeof(short));
    short* g_buf = (short*)alloc((size_t)N_NODES * D * sizeof(short));
    short* z_buf = (short*)alloc((size_t)N_NODES * D * sizeof(short));

    const int nscan = (N_NODES + 2047) / 2048;

    // CSR build, bucketed
    zero_n_kernel<<<1, 256, 0, stream>>>(bucket_cnt, NB);
    bucketA_kernel<<<N_EDGES / EPB, 256, 0, stream>>>(src, dst, bucket_cnt, bucketbuf);
    bucketB1_kernel<<<NB, 256, 0, stream>>>(bucket_cnt, bucketbuf, deg);
    scan1_kernel<<<nscan, 256, 0, stream>>>(deg, incl, bsum);
    scan2_kernel<<<1, 64, 0, stream>>>(bsum, nscan);
    scan3_kernel<<<(N_NODES + 255) / 256, 256, 0, stream>>>(deg, incl, bsum, start, cursor);
    bucketB2_kernel<<<NB, 256, 0, stream>>>(bucket_cnt, bucketbuf, cursor, csr_src);

    gproj_kernel<<<dim3(B_GRAPHS, L_LAYERS), D, 0, stream>>>(gs, statWs, statBs, gproj);
    wconv_kernel<<<dim3(64, 7), 256, 0, stream>>>(W1s, W2s, fcW, wt);

    const int agg_blocks = N_NODES / 16;         // 6250
    const int mlp_blocks = (N_NODES + 63) / 64;  // 1563

    // g0 = bf16(x) @ W1_0
    initgemm_kernel<<<mlp_blocks, 256, 0, stream>>>(x, wt + 0 * D * D, g_buf);

    // layer 0: g -> z -> (W2_0, W1_1) -> g
    agg_ep_kernel<<<agg_blocks, 256, 0, stream>>>(g_buf, start, csr_src, b1s + 0 * D,
                                                  gammas + 0 * D, betas + 0 * D, means + 0 * D,
                                                  vars + 0 * D, z_buf);
    mlp2_kernel<false><<<mlp_blocks, 256, 0, stream>>>(
        z_buf, wt + 3 * D * D, b2s + 0 * D, gproj + 0 * B_GRAPHS * D, batch,
        wt + 1 * D * D, nullptr, nullptr, g_buf);
    // layer 1: g -> z -> (W2_1, W1_2) -> g
    agg_ep_kernel<<<agg_blocks, 256, 0, stream>>>(g_buf, start, csr_src, b1s + 1 * D,
                                                  gammas + 1 * D, betas + 1 * D, means + 1 * D,
                                                  vars + 1 * D, z_buf);
    mlp2_kernel<false><<<mlp_blocks, 256, 0, stream>>>(
        z_buf, wt + 4 * D * D, b2s + 1 * D, gproj + 1 * B_GRAPHS * D, batch,
        wt + 2 * D * D, nullptr, nullptr, g_buf);
    // layer 2: g -> z -> (W2_2, fcW) -> out (f32)
    agg_ep_kernel<<<agg_blocks, 256, 0, stream>>>(g_buf, start, csr_src, b1s + 2 * D,
                                                  gammas + 2 * D, betas + 2 * D, means + 2 * D,
                                                  vars + 2 * D, z_buf);
    mlp2_kernel<true><<<mlp_blocks, 256, 0, stream>>>(
        z_buf, wt + 5 * D * D, b2s + 2 * D, gproj + 2 * B_GRAPHS * D, batch,
        wt + 6 * D * D, fcB, out, nullptr);
}

// Round 13
// 385.402 us; speedup vs baseline: 1.1154x; 1.1154x over previous
//
#include <hip/hip_runtime.h>
#include <math.h>

#define N_NODES 100000
#define N_EDGES 1600000
#define D 128
#define L_LAYERS 3
#define P_STATS 7
#define B_GRAPHS 64
#define BN_EPS 1e-5f
#define NEG_SLOPE 0.2f

#define NB 196        // buckets of 512 dst nodes
#define BCAP 10240    // mean 8192, sigma ~90 -> 22 sigma headroom
#define EPB 6400

typedef __attribute__((ext_vector_type(8))) short bf16x8;
typedef __attribute__((ext_vector_type(4))) float f32x4;

static __device__ __forceinline__ short f2bf(float f) {
    union { float f; unsigned u; } v;
    v.f = f;
    unsigned r = v.u + 0x7fffu + ((v.u >> 16) & 1u);  // RNE
    return (short)(r >> 16);
}

static __device__ __forceinline__ float bf2f(short s) {
    union { unsigned u; float f; } v;
    v.u = ((unsigned)(unsigned short)s) << 16;
    return v.f;
}

// ---------------- setup: wconv (448 blocks) + gproj (96) + zero bucket_cnt (1) ----------------
__global__ __launch_bounds__(256) void setup_kernel(const float* __restrict__ W1s,
                                                    const float* __restrict__ W2s,
                                                    const float* __restrict__ fcW,
                                                    short* __restrict__ wt,
                                                    const float* __restrict__ gs,
                                                    const float* __restrict__ statWs,
                                                    const float* __restrict__ statBs,
                                                    float* __restrict__ gproj,
                                                    int* __restrict__ bucket_cnt) {
    const int bid = blockIdx.x;
    const int tid = threadIdx.x;
    if (bid < 448) {
        // W[k][n] f32 -> Wt[n][k] bf16; matrices 0..2=W1s, 3..5=W2s, 6=fcW
        int mid = bid >> 6;
        int chunk = bid & 63;
        const float* src = (mid < 3) ? (W1s + mid * D * D)
                                     : ((mid < 6) ? (W2s + (mid - 3) * D * D) : fcW);
        short* dstm = wt + mid * D * D;
        int i = chunk * 256 + tid;
        int k = i >> 7, n = i & 127;
        dstm[n * D + k] = f2bf(src[i]);
    } else if (bid < 448 + 96) {
        int p = (bid - 448) * 2 + (tid >> 7);  // 0..191 (b,l) pairs
        int j = tid & 127;
        int b = p & 63;
        int l = p >> 6;
        float acc = statBs[l * D + j];
#pragma unroll
        for (int q = 0; q < P_STATS; ++q) {
            float g = gs[b * P_STATS + q];
            if (g != g) g = -100.0f;
            acc += g * statWs[(l * P_STATS + q) * D + j];
        }
        gproj[(l * B_GRAPHS + b) * D + j] = acc;
    } else {
        if (tid < NB) bucket_cnt[tid] = 0;
    }
}

// ---------------- CSR pass A: partition edges into packed per-bucket buffers ----------------
__global__ __launch_bounds__(256) void bucketA_kernel(const int* __restrict__ src,
                                                      const int* __restrict__ dst,
                                                      int* __restrict__ bucket_cnt,
                                                      int* __restrict__ bucketbuf) {
    __shared__ int hist[NB], base[NB], loc[NB];
    const int tid = threadIdx.x;
    const int e0 = blockIdx.x * EPB;
    for (int i = tid; i < NB; i += 256) { hist[i] = 0; loc[i] = 0; }
    __syncthreads();
    for (int i = tid; i < EPB; i += 256) {
        int d = dst[e0 + i];
        atomicAdd(&hist[d >> 9], 1);
    }
    __syncthreads();
    for (int i = tid; i < NB; i += 256)
        base[i] = hist[i] ? atomicAdd(&bucket_cnt[i], hist[i]) : 0;
    __syncthreads();
    for (int i = tid; i < EPB; i += 256) {
        int s = src[e0 + i];
        int d = dst[e0 + i];
        int b = d >> 9;
        int off = atomicAdd(&loc[b], 1);
        int idx = base[b] + off;
        if (idx < BCAP) bucketbuf[(size_t)b * BCAP + idx] = (s << 9) | (d & 511);
    }
}

// ---------------- CSR pass B: per-bucket hist + scan + start[] + local scatter ----------------
// csr is bucket-major: bucket b owns [sum cnt[0..b), +cnt[b]); within, node-local order.
__global__ __launch_bounds__(256) void bucketB_kernel(const int* __restrict__ bucket_cnt,
                                                      const int* __restrict__ bucketbuf,
                                                      int* __restrict__ start,
                                                      int* __restrict__ csr_src) {
    __shared__ int hist[512];
    __shared__ int incl[512];
    __shared__ int cursor[512];
    __shared__ int red[256];
    __shared__ int sbase_sh;
    const int b = blockIdx.x;
    const int tid = threadIdx.x;
    const int cnt_b = min(bucket_cnt[b], BCAP);

    // bucket base = sum of clamped counts of buckets < b
    int partial = 0;
    for (int i = tid; i < b; i += 256) partial += min(bucket_cnt[i], BCAP);
    red[tid] = partial;
    __syncthreads();
    for (int off = 128; off > 0; off >>= 1) {
        if (tid < off) red[tid] += red[tid + off];
        __syncthreads();
    }
    if (tid == 0) sbase_sh = red[0];

    hist[tid] = 0;
    hist[tid + 256] = 0;
    __syncthreads();
    const int* bb = bucketbuf + (size_t)b * BCAP;
    for (int i = tid; i < cnt_b; i += 256) atomicAdd(&hist[bb[i] & 511], 1);
    __syncthreads();
    incl[tid] = hist[tid];
    incl[tid + 256] = hist[tid + 256];
    __syncthreads();
    // Hillis-Steele inclusive scan over 512, 2 elems/thread
    for (int off = 1; off < 512; off <<= 1) {
        int i1 = tid + 256;
        int v0 = (tid >= off) ? incl[tid - off] : 0;
        int v1 = (i1 >= off) ? incl[i1 - off] : 0;
        __syncthreads();
        incl[tid] += v0;
        incl[i1] += v1;
        __syncthreads();
    }
    const int sbase = sbase_sh;
    int excl0 = incl[tid] - hist[tid];
    int excl1 = incl[tid + 256] - hist[tid + 256];
    cursor[tid] = excl0;
    cursor[tid + 256] = excl1;
    const int nbase = b << 9;
    if (nbase + tid < N_NODES) start[nbase + tid] = sbase + excl0;
    if (nbase + tid + 256 < N_NODES) start[nbase + tid + 256] = sbase + excl1;
    if (b == NB - 1 && tid == 0) start[N_NODES] = sbase + incl[511];
    __syncthreads();
    // scatter into this bucket's csr window (L2-resident) via LDS cursors
    for (int i = tid; i < cnt_b; i += 256) {
        int e = bb[i];
        int pos = atomicAdd(&cursor[e & 511], 1);
        csr_src[sbase + pos] = e >> 9;
    }
}

// ---------------- aggregation over g + fused bias/LReLU/BN epilogue ----------------
__global__ __launch_bounds__(256) void agg_ep_kernel(const short* __restrict__ g,
                                                     const int* __restrict__ start,
                                                     const int* __restrict__ csr_src,
                                                     const float* __restrict__ b1,
                                                     const float* __restrict__ gamma,
                                                     const float* __restrict__ beta,
                                                     const float* __restrict__ mean,
                                                     const float* __restrict__ var,
                                                     short* __restrict__ z) {
    int node = blockIdx.x * 16 + (threadIdx.x >> 4);
    int c8 = threadIdx.x & 15;
    const bf16x8* g8 = (const bf16x8*)g;

    bf16x8 own = g8[node * 16 + c8];
    float acc[8];
#pragma unroll
    for (int i = 0; i < 8; ++i) acc[i] = bf2f(own[i]);

    int s = start[node];
    int e = start[node + 1];
    int k = s;
    for (; k + 4 <= e; k += 4) {
        int sn0 = csr_src[k];
        int sn1 = csr_src[k + 1];
        int sn2 = csr_src[k + 2];
        int sn3 = csr_src[k + 3];
        bf16x8 v0 = g8[sn0 * 16 + c8];
        bf16x8 v1 = g8[sn1 * 16 + c8];
        bf16x8 v2 = g8[sn2 * 16 + c8];
        bf16x8 v3 = g8[sn3 * 16 + c8];
#pragma unroll
        for (int i = 0; i < 8; ++i) acc[i] += bf2f(v0[i]);
#pragma unroll
        for (int i = 0; i < 8; ++i) acc[i] += bf2f(v1[i]);
#pragma unroll
        for (int i = 0; i < 8; ++i) acc[i] += bf2f(v2[i]);
#pragma unroll
        for (int i = 0; i < 8; ++i) acc[i] += bf2f(v3[i]);
    }
    for (; k < e; ++k) {
        int sn0 = csr_src[k];
        bf16x8 v0 = g8[sn0 * 16 + c8];
#pragma unroll
        for (int i = 0; i < 8; ++i) acc[i] += bf2f(v0[i]);
    }

    const int f0 = c8 * 8;
    float4 bb0 = *(const float4*)&b1[f0];
    float4 bb1 = *(const float4*)&b1[f0 + 4];
    float4 gm0 = *(const float4*)&gamma[f0];
    float4 gm1 = *(const float4*)&gamma[f0 + 4];
    float4 bt0 = *(const float4*)&beta[f0];
    float4 bt1 = *(const float4*)&beta[f0 + 4];
    float4 mn0 = *(const float4*)&mean[f0];
    float4 mn1 = *(const float4*)&mean[f0 + 4];
    float4 vr0 = *(const float4*)&var[f0];
    float4 vr1 = *(const float4*)&var[f0 + 4];
    float bbv[8] = {bb0.x, bb0.y, bb0.z, bb0.w, bb1.x, bb1.y, bb1.z, bb1.w};
    float gmv[8] = {gm0.x, gm0.y, gm0.z, gm0.w, gm1.x, gm1.y, gm1.z, gm1.w};
    float btv[8] = {bt0.x, bt0.y, bt0.z, bt0.w, bt1.x, bt1.y, bt1.z, bt1.w};
    float mnv[8] = {mn0.x, mn0.y, mn0.z, mn0.w, mn1.x, mn1.y, mn1.z, mn1.w};
    float vrv[8] = {vr0.x, vr0.y, vr0.z, vr0.w, vr1.x, vr1.y, vr1.z, vr1.w};

    short pk[8];
#pragma unroll
    for (int i = 0; i < 8; ++i) {
        float t = acc[i] + bbv[i];
        t = (t > 0.f) ? t : NEG_SLOPE * t;
        float sc = gmv[i] * rsqrtf(vrv[i] + BN_EPS);
        t = t * sc + (btv[i] - mnv[i] * sc);
        pk[i] = f2bf(t);
    }
    *(bf16x8*)&z[node * D + f0] = *(bf16x8*)pk;
}

// ---------------- init GEMM: g0 = bf16(x) @ W1_0 ----------------
__global__ __launch_bounds__(256, 4) void initgemm_kernel(const float* __restrict__ x,
                                                          const short* __restrict__ Wt,
                                                          short* __restrict__ g_out) {
    __shared__ short sy[64 * 128];
    const int tid = threadIdx.x;
    const int wid = tid >> 6;
    const int lane = tid & 63;
    const int lr = lane & 15;
    const int lk = lane >> 4;

    const int nlBase = (wid >> 1) * 32;
    const int nodeBase = blockIdx.x * 64 + nlBase;
    const int featBase = (wid & 1) * 64;

    int nIdx[2];
#pragma unroll
    for (int mt = 0; mt < 2; ++mt) {
        int n = nodeBase + mt * 16 + lr;
        nIdx[mt] = (n < N_NODES) ? n : (N_NODES - 1);
    }

    f32x4 acc[4][2];
#pragma unroll
    for (int ft = 0; ft < 4; ++ft)
#pragma unroll
        for (int mt = 0; mt < 2; ++mt)
            acc[ft][mt] = (f32x4)(0.0f);

#pragma unroll
    for (int kt = 0; kt < 4; ++kt) {
        bf16x8 wfk[4];
#pragma unroll
        for (int ft = 0; ft < 4; ++ft)
            wfk[ft] = *(const bf16x8*)&Wt[(featBase + ft * 16 + lr) * D + kt * 32 + lk * 8];
        bf16x8 mf[2];
#pragma unroll
        for (int mt = 0; mt < 2; ++mt) {
            const float4* xp = (const float4*)&x[nIdx[mt] * D + kt * 32 + lk * 8];
            float4 a = xp[0], b = xp[1];
            short q[8];
            q[0] = f2bf(a.x); q[1] = f2bf(a.y); q[2] = f2bf(a.z); q[3] = f2bf(a.w);
            q[4] = f2bf(b.x); q[5] = f2bf(b.y); q[6] = f2bf(b.z); q[7] = f2bf(b.w);
            mf[mt] = *(bf16x8*)q;
        }
#pragma unroll
        for (int ft = 0; ft < 4; ++ft)
#pragma unroll
            for (int mt = 0; mt < 2; ++mt)
                acc[ft][mt] = __builtin_amdgcn_mfma_f32_16x16x32_bf16(wfk[ft], mf[mt],
                                                                      acc[ft][mt], 0, 0, 0);
    }

#pragma unroll
    for (int ft = 0; ft < 4; ++ft) {
        int f0 = featBase + ft * 16 + lk * 4;
#pragma unroll
        for (int mt = 0; mt < 2; ++mt) {
            int nl = nlBase + mt * 16 + lr;
            short4 pk;
#pragma unroll
            for (int r = 0; r < 4; ++r) ((short*)&pk)[r] = f2bf(acc[ft][mt][r]);
            int byteoff = nl * 256 + f0 * 2;
            byteoff ^= (nl & 7) << 4;
            *(short4*)((char*)sy + byteoff) = pk;
        }
    }
    __syncthreads();
#pragma unroll
    for (int it = 0; it < 4; ++it) {
        int c = tid + it * 256;
        int nl = c >> 4;
        int c8 = c & 15;
        int node = blockIdx.x * 64 + nl;
        if (node < N_NODES) {
            int byteoff = nl * 256 + c8 * 16;
            byteoff ^= (nl & 7) << 4;
            bf16x8 v = *(const bf16x8*)((char*)sy + byteoff);
            *(bf16x8*)&g_out[node * D + c8 * 8] = v;
        }
    }
}

// ---------------- MLP: y=LReLU(z@W2+b2)+gproj -> h; g=h@Wn (or out=h@fcW+fcB) ----------------
template <bool FINAL>
__global__ __launch_bounds__(256, 4) void mlp2_kernel(
    const short* __restrict__ z,
    const short* __restrict__ W2t,
    const float* __restrict__ b2,
    const float* __restrict__ gproj, const int* __restrict__ batch,
    const short* __restrict__ Wnt,
    const float* __restrict__ fcb,
    float* __restrict__ outf, short* __restrict__ g_out) {
    __shared__ short sy[64 * 128];
    __shared__ float sB2[128], sFC[128];

    const int tid = threadIdx.x;
    const int wid = tid >> 6;
    const int lane = tid & 63;
    const int lr = lane & 15;
    const int lk = lane >> 4;

    if (tid < 128) {
        sB2[tid] = b2[tid];
        if (FINAL) sFC[tid] = fcb[tid];
    }
    __syncthreads();

    const int nlBase = (wid >> 1) * 32;
    const int nodeBase = blockIdx.x * 64 + nlBase;
    const int featBase = (wid & 1) * 64;

    int nIdx[2];
#pragma unroll
    for (int mt = 0; mt < 2; ++mt) {
        int n = nodeBase + mt * 16 + lr;
        nIdx[mt] = (n < N_NODES) ? n : (N_NODES - 1);
    }

    f32x4 acc[4][2];
#pragma unroll
    for (int ft = 0; ft < 4; ++ft)
#pragma unroll
        for (int mt = 0; mt < 2; ++mt)
            acc[ft][mt] = (f32x4)(0.0f);

    // GEMM A: z @ W2
#pragma unroll
    for (int kt = 0; kt < 4; ++kt) {
        bf16x8 wfk[4];
#pragma unroll
        for (int ft = 0; ft < 4; ++ft)
            wfk[ft] = *(const bf16x8*)&W2t[(featBase + ft * 16 + lr) * D + kt * 32 + lk * 8];
        bf16x8 zf[2];
#pragma unroll
        for (int mt = 0; mt < 2; ++mt)
            zf[mt] = *(const bf16x8*)&z[nIdx[mt] * D + kt * 32 + lk * 8];
#pragma unroll
        for (int ft = 0; ft < 4; ++ft)
#pragma unroll
            for (int mt = 0; mt < 2; ++mt)
                acc[ft][mt] = __builtin_amdgcn_mfma_f32_16x16x32_bf16(wfk[ft], zf[mt],
                                                                      acc[ft][mt], 0, 0, 0);
    }

    // epilogue: +b2, LReLU, +gproj -> h bf16 -> LDS (swizzled)
#pragma unroll
    for (int ft = 0; ft < 4; ++ft) {
        int f0 = featBase + ft * 16 + lk * 4;
#pragma unroll
        for (int mt = 0; mt < 2; ++mt) {
            int nl = nlBase + mt * 16 + lr;
            int bid = batch[nIdx[mt]];
            const float4 gp = *(const float4*)&gproj[bid * D + f0];
            short4 pk;
            float v0 = acc[ft][mt][0] + sB2[f0 + 0]; v0 = (v0 > 0.f) ? v0 : NEG_SLOPE * v0; v0 += gp.x;
            float v1 = acc[ft][mt][1] + sB2[f0 + 1]; v1 = (v1 > 0.f) ? v1 : NEG_SLOPE * v1; v1 += gp.y;
            float v2 = acc[ft][mt][2] + sB2[f0 + 2]; v2 = (v2 > 0.f) ? v2 : NEG_SLOPE * v2; v2 += gp.z;
            float v3 = acc[ft][mt][3] + sB2[f0 + 3]; v3 = (v3 > 0.f) ? v3 : NEG_SLOPE * v3; v3 += gp.w;
            pk.x = f2bf(v0); pk.y = f2bf(v1); pk.z = f2bf(v2); pk.w = f2bf(v3);
            int byteoff = nl * 256 + f0 * 2;
            byteoff ^= (nl & 7) << 4;
            *(short4*)((char*)sy + byteoff) = pk;
        }
    }
    __syncthreads();

    // GEMM B: h @ Wn (h from LDS)
#pragma unroll
    for (int ft = 0; ft < 4; ++ft)
#pragma unroll
        for (int mt = 0; mt < 2; ++mt)
            acc[ft][mt] = (f32x4)(0.0f);

#pragma unroll
    for (int kt = 0; kt < 4; ++kt) {
        bf16x8 wfk[4];
#pragma unroll
        for (int ft = 0; ft < 4; ++ft)
            wfk[ft] = *(const bf16x8*)&Wnt[(featBase + ft * 16 + lr) * D + kt * 32 + lk * 8];
        bf16x8 hf[2];
#pragma unroll
        for (int mt = 0; mt < 2; ++mt) {
            int nl = nlBase + mt * 16 + lr;
            int byteoff = nl * 256 + kt * 64 + lk * 16;
            byteoff ^= (nl & 7) << 4;
            hf[mt] = *(const bf16x8*)((char*)sy + byteoff);
        }
#pragma unroll
        for (int ft = 0; ft < 4; ++ft)
#pragma unroll
            for (int mt = 0; mt < 2; ++mt)
                acc[ft][mt] = __builtin_amdgcn_mfma_f32_16x16x32_bf16(wfk[ft], hf[mt],
                                                                      acc[ft][mt], 0, 0, 0);
    }

    if (FINAL) {
#pragma unroll
        for (int mt = 0; mt < 2; ++mt) {
            int node = nodeBase + mt * 16 + lr;
            if (node >= N_NODES) continue;
#pragma unroll
            for (int ft = 0; ft < 4; ++ft) {
                int f0 = featBase + ft * 16 + lk * 4;
                float4 o;
                o.x = acc[ft][mt][0] + sFC[f0 + 0];
                o.y = acc[ft][mt][1] + sFC[f0 + 1];
                o.z = acc[ft][mt][2] + sFC[f0 + 2];
                o.w = acc[ft][mt][3] + sFC[f0 + 3];
                *(float4*)&outf[node * D + f0] = o;
            }
        }
        return;
    }

    __syncthreads();
#pragma unroll
    for (int ft = 0; ft < 4; ++ft) {
        int f0 = featBase + ft * 16 + lk * 4;
#pragma unroll
        for (int mt = 0; mt < 2; ++mt) {
            int nl = nlBase + mt * 16 + lr;
            short4 pk;
#pragma unroll
            for (int r = 0; r < 4; ++r) ((short*)&pk)[r] = f2bf(acc[ft][mt][r]);
            int byteoff = nl * 256 + f0 * 2;
            byteoff ^= (nl & 7) << 4;
            *(short4*)((char*)sy + byteoff) = pk;
        }
    }
    __syncthreads();
#pragma unroll
    for (int it = 0; it < 4; ++it) {
        int c = tid + it * 256;
        int nl = c >> 4;
        int c8 = c & 15;
        int node = blockIdx.x * 64 + nl;
        if (node < N_NODES) {
            int byteoff = nl * 256 + c8 * 16;
            byteoff ^= (nl & 7) << 4;
            bf16x8 v = *(const bf16x8*)((char*)sy + byteoff);
            *(bf16x8*)&g_out[node * D + c8 * 8] = v;
        }
    }
}

// ---------------- launch ----------------

extern "C" void kernel_launch(void* const* d_in, const int* in_sizes, int n_in,
                              void* d_out, int out_size, void* d_ws, size_t ws_size,
                              hipStream_t stream) {
    const float* x = (const float*)d_in[0];
    const int* ei = (const int*)d_in[1];
    const int* src = ei;
    const int* dst = ei + N_EDGES;
    const int* batch = (const int*)d_in[2];
    const float* gs = (const float*)d_in[3];
    const float* W1s = (const float*)d_in[4];
    const float* b1s = (const float*)d_in[5];
    const float* gammas = (const float*)d_in[6];
    const float* betas = (const float*)d_in[7];
    const float* means = (const float*)d_in[8];
    const float* vars = (const float*)d_in[9];
    const float* W2s = (const float*)d_in[10];
    const float* b2s = (const float*)d_in[11];
    const float* statWs = (const float*)d_in[12];
    const float* statBs = (const float*)d_in[13];
    const float* fcW = (const float*)d_in[14];
    const float* fcB = (const float*)d_in[15];
    float* out = (float*)d_out;

    char* ws = (char*)d_ws;
    auto alloc = [&](size_t bytes) {
        char* p = ws;
        ws += (bytes + 255) / 256 * 256;
        return p;
    };
    int* start = (int*)alloc((N_NODES + 1) * sizeof(int));
    int* csr_src = (int*)alloc(N_EDGES * sizeof(int));
    int* bucket_cnt = (int*)alloc(NB * sizeof(int));
    int* bucketbuf = (int*)alloc((size_t)NB * BCAP * sizeof(int));
    float* gproj = (float*)alloc((size_t)L_LAYERS * B_GRAPHS * D * sizeof(float));
    short* wt = (short*)alloc((size_t)7 * D * D * sizeof(short));
    short* g_buf = (short*)alloc((size_t)N_NODES * D * sizeof(short));
    short* z_buf = (short*)alloc((size_t)N_NODES * D * sizeof(short));

    // setup: wconv + gproj + zero bucket_cnt (one dispatch)
    setup_kernel<<<545, 256, 0, stream>>>(W1s, W2s, fcW, wt, gs, statWs, statBs, gproj,
                                          bucket_cnt);
    // CSR build: 2 dispatches
    bucketA_kernel<<<N_EDGES / EPB, 256, 0, stream>>>(src, dst, bucket_cnt, bucketbuf);
    bucketB_kernel<<<NB, 256, 0, stream>>>(bucket_cnt, bucketbuf, start, csr_src);

    const int agg_blocks = N_NODES / 16;         // 6250
    const int mlp_blocks = (N_NODES + 63) / 64;  // 1563

    // g0 = bf16(x) @ W1_0
    initgemm_kernel<<<mlp_blocks, 256, 0, stream>>>(x, wt + 0 * D * D, g_buf);

    // layer 0
    agg_ep_kernel<<<agg_blocks, 256, 0, stream>>>(g_buf, start, csr_src, b1s + 0 * D,
                                                  gammas + 0 * D, betas + 0 * D, means + 0 * D,
                                                  vars + 0 * D, z_buf);
    mlp2_kernel<false><<<mlp_blocks, 256, 0, stream>>>(
        z_buf, wt + 3 * D * D, b2s + 0 * D, gproj + 0 * B_GRAPHS * D, batch,
        wt + 1 * D * D, nullptr, nullptr, g_buf);
    // layer 1
    agg_ep_kernel<<<agg_blocks, 256, 0, stream>>>(g_buf, start, csr_src, b1s + 1 * D,
                                                  gammas + 1 * D, betas + 1 * D, means + 1 * D,
                                                  vars + 1 * D, z_buf);
    mlp2_kernel<false><<<mlp_blocks, 256, 0, stream>>>(
        z_buf, wt + 4 * D * D, b2s + 1 * D, gproj + 1 * B_GRAPHS * D, batch,
        wt + 2 * D * D, nullptr, nullptr, g_buf);
    // layer 2 (+ fc_out)
    agg_ep_kernel<<<agg_blocks, 256, 0, stream>>>(g_buf, start, csr_src, b1s + 2 * D,
                                                  gammas + 2 * D, betas + 2 * D, means + 2 * D,
                                                  vars + 2 * D, z_buf);
    mlp2_kernel<true><<<mlp_blocks, 256, 0, stream>>>(
        z_buf, wt + 5 * D * D, b2s + 2 * D, gproj + 2 * B_GRAPHS * D, batch,
        wt + 6 * D * D, fcB, out, nullptr);
}